// Round 3
// baseline (88.078 us; speedup 1.0000x reference)
//
#include <hip/hip_runtime.h>
#include <math.h>

#define SIDE 0.6

// One 64-lane wave per ray (S = 64, lane == sample index).
// f64 pipeline: matches the f64 numpy reference through the discontinuous
// decisions (searchsorted bin choice, denom<1e-5 branch, inside-box test).
__global__ __launch_bounds__(256) void neus_sample_kernel(
    const float* __restrict__ rays_o,
    const float* __restrict__ rays_d,
    const float* __restrict__ z_vals,
    const float* __restrict__ sdf,
    const float* __restrict__ inv_s,
    float* __restrict__ out,
    int B, int n_imp, double u0, double du)
{
    const int lane = threadIdx.x & 63;
    const int wave = threadIdx.x >> 6;
    const int ray  = blockIdx.x * 4 + wave;
    if (ray >= B) return;               // wave-uniform

    // ---- coalesced f32 loads, upcast to f64 ----
    const double z = (double)z_vals[(size_t)ray * 64 + lane];
    const double s = (double)sdf   [(size_t)ray * 64 + lane];
    double isv = 0.0;
    if (lane < 63) isv = (double)inv_s[(size_t)ray * 63 + lane];

    const double ox = (double)rays_o[(size_t)ray*3+0];
    const double oy = (double)rays_o[(size_t)ray*3+1];
    const double oz = (double)rays_o[(size_t)ray*3+2];
    const double dx = (double)rays_d[(size_t)ray*3+0];
    const double dy = (double)rays_d[(size_t)ray*3+1];
    const double dz = (double)rays_d[(size_t)ray*3+2];

    // ---- inside-box test ----
    const double px = ox + dx*z, py = oy + dy*z, pz = oz + dz*z;
    const double inner = (fabs(px) <= SIDE && fabs(py) <= SIDE && fabs(pz) <= SIDE) ? 1.0 : 0.0;

    // neighbor (i+1) values
    const double next_s  = __shfl_down(s, 1);
    const double next_z  = __shfl_down(z, 1);
    const double inner_n = __shfl_down(inner, 1);

    // ---- interval quantities (valid for lane < 63) ----
    const double inside = ((inner > 0.5) || (inner_n > 0.5)) ? 1.0 : 0.0;
    const double mid    = 0.5 * (s + next_s);
    const double cv0    = (next_s - s) / (next_z - z + 1e-5);
    double prevc = __shfl_up(cv0, 1);
    if (lane == 0) prevc = 0.0;                        // prev_cos[0] = 0
    double cv = fmin(prevc, cv0);
    cv = fmin(fmax(cv, -1000.0), 0.0) * inside;        // clip * inside
    const double dist = next_z - z;

    const double arg_p = (mid - cv * dist * 0.5) * isv;
    const double arg_n = (mid + cv * dist * 0.5) * isv;
    const double pcdf  = 1.0 / (1.0 + exp(-arg_p));
    const double ncdf  = 1.0 / (1.0 + exp(-arg_n));
    const double alpha = (pcdf - ncdf + 1e-5) / (pcdf + 1e-5);

    // ---- exclusive cumprod of (1 - alpha + 1e-7): transmittance ----
    double g = (lane < 63) ? (1.0 - alpha + 1e-7) : 1.0;
    double p = g;
    #pragma unroll
    for (int off = 1; off < 64; off <<= 1) {
        double t = __shfl_up(p, off);
        if (lane >= off) p *= t;
    }
    double trans = __shfl_up(p, 1);
    if (lane == 0) trans = 1.0;

    // weights (+ sample_pdf's +1e-5); lane 63 holds 0 so scan total = sum
    const double w = (lane < 63) ? (alpha * trans + 1e-5) : 0.0;

    // ---- inclusive cumsum -> exclusive -> normalized CDF ----
    double sc = w;
    #pragma unroll
    for (int off = 1; off < 64; off <<= 1) {
        double t = __shfl_up(sc, off);
        if (lane >= off) sc += t;
    }
    const double total = __shfl(sc, 63);    // sum of all 63 weights
    double excl = __shfl_up(sc, 1);
    if (lane == 0) excl = 0.0;
    const double cdf = excl / total;        // cdf[0]=0, cdf[63]=1

    // ---- searchsorted(cdf, u, side='right'): 7-step binary search ----
    // ind in [0,64]: 65 candidates -> ceil(log2(65)) = 7 halvings.
    // (6 iterations can leave hi-lo==1: the rounds-1/2 absmax=0.234375
    //  bug — one-bin mis-select; max bin width happens to be ~0.234.)
    // Guard lo<hi so early-converged lanes don't corrupt their answer;
    // __shfl stays unconditionally executed (wave-uniform control).
    const double u = u0 + du * (double)lane;   // exact multiples of 1/32
    int lo = 0, hi = 64;
    #pragma unroll
    for (int it = 0; it < 7; ++it) {
        const int m  = (lo + hi) >> 1;         // in [lo, hi)
        const double cm = __shfl(cdf, m);      // m<=63 always (hi<=64, lo<=hi)
        if (lo < hi) {
            if (cm <= u) lo = m + 1; else hi = m;
        }
    }                                          // after 7: lo == hi
    const int ind   = lo;                      // first idx with cdf > u
    const int below = max(ind - 1, 0);
    const int above = min(ind, 63);

    const double cb = __shfl(cdf, below);
    const double ca = __shfl(cdf, above);
    const double bb = __shfl(z, below);
    const double ba = __shfl(z, above);

    double denom = ca - cb;
    denom = (denom < 1e-5) ? 1.0 : denom;
    const double t   = (u - cb) / denom;
    const double res = bb + t * (ba - bb);

    if (lane < n_imp) out[(size_t)ray * n_imp + lane] = (float)res;
}

extern "C" void kernel_launch(void* const* d_in, const int* in_sizes, int n_in,
                              void* d_out, int out_size, void* d_ws, size_t ws_size,
                              hipStream_t stream) {
    const float* rays_o = (const float*)d_in[0];
    const float* rays_d = (const float*)d_in[1];
    const float* z_vals = (const float*)d_in[2];
    const float* sdf    = (const float*)d_in[3];
    const float* inv_s  = (const float*)d_in[4];
    float* out = (float*)d_out;

    const int B = in_sizes[0] / 3;          // 131072
    const int n = out_size / B;             // n_importance = 16
    const double u0 = 0.5 / (double)n;
    const double du = (n > 1) ? ((1.0 - 1.0 / (double)n) / (double)(n - 1)) : 0.0;

    const int grid = (B + 3) / 4;           // 4 waves (rays) per 256-thread block
    neus_sample_kernel<<<grid, 256, 0, stream>>>(rays_o, rays_d, z_vals, sdf, inv_s,
                                                 out, B, n, u0, du);
}

// Round 4
// 84.382 us; speedup vs baseline: 1.0438x; 1.0438x over previous
//
#include <hip/hip_runtime.h>
#include <math.h>

#define SIDE 0.6

// Fast branch-free f64 exp for x in [-350, 350]; rel err ~1e-15.
// k*LN2HI is exact (LN2HI has 21 trailing zero bits, |k| <= 506 = 10 bits).
__device__ __forceinline__ double exp_fast(double x) {
    const double INVLN2 = 1.44269504088896338700e+00;
    const double LN2HI  = 6.93147180369123816490e-01;   // 0x3FE62E42FEE00000
    const double LN2LO  = 1.90821492927058770002e-10;   // 0x3DEA39EF35793C76
    const double kd = __builtin_rint(x * INVLN2);
    const int    k  = (int)kd;
    double r = __builtin_fma(-kd, LN2HI, x);
    r        = __builtin_fma(-kd, LN2LO, r);
    // Taylor exp(r), |r| <= ln2/2 = 0.3466: trunc err r^13/13! ~ 1.7e-16 rel
    double p =               2.08767569878681e-09;      // 1/12!
    p = __builtin_fma(p, r,  2.50521083854417e-08);     // 1/11!
    p = __builtin_fma(p, r,  2.75573192239859e-07);     // 1/10!
    p = __builtin_fma(p, r,  2.75573192239859e-06);     // 1/9!
    p = __builtin_fma(p, r,  2.48015873015873e-05);     // 1/8!
    p = __builtin_fma(p, r,  1.98412698412698e-04);     // 1/7!
    p = __builtin_fma(p, r,  1.38888888888889e-03);     // 1/6!
    p = __builtin_fma(p, r,  8.33333333333333e-03);     // 1/5!
    p = __builtin_fma(p, r,  4.16666666666667e-02);     // 1/4!
    p = __builtin_fma(p, r,  1.66666666666667e-01);     // 1/3!
    p = __builtin_fma(p, r,  5.00000000000000e-01);     // 1/2!
    p = __builtin_fma(p, r,  1.0);
    p = __builtin_fma(p, r,  1.0);
    const long long bits = (long long)(1023 + k) << 52; // 2^k, k in [-506,506]
    return p * __longlong_as_double(bits);
}

// One 64-lane wave per ray (S = 64, lane == sample index).
// f64 pipeline: matches the f64 numpy reference through the discontinuous
// decisions (searchsorted bin choice, denom<1e-5 branch, inside-box test).
__global__ __launch_bounds__(256) void neus_sample_kernel(
    const float* __restrict__ rays_o,
    const float* __restrict__ rays_d,
    const float* __restrict__ z_vals,
    const float* __restrict__ sdf,
    const float* __restrict__ inv_s,
    float* __restrict__ out,
    int B, int n_imp, double u0, double du)
{
    const int lane = threadIdx.x & 63;
    const int wave = threadIdx.x >> 6;
    const int ray  = blockIdx.x * 4 + wave;
    if (ray >= B) return;               // wave-uniform

    // ---- coalesced f32 loads, upcast to f64 ----
    const double z = (double)z_vals[(size_t)ray * 64 + lane];
    const double s = (double)sdf   [(size_t)ray * 64 + lane];
    double isv = 0.0;
    if (lane < 63) isv = (double)inv_s[(size_t)ray * 63 + lane];

    const double ox = (double)rays_o[(size_t)ray*3+0];
    const double oy = (double)rays_o[(size_t)ray*3+1];
    const double oz = (double)rays_o[(size_t)ray*3+2];
    const double dx = (double)rays_d[(size_t)ray*3+0];
    const double dy = (double)rays_d[(size_t)ray*3+1];
    const double dz = (double)rays_d[(size_t)ray*3+2];

    // ---- inside-box test ----
    const double px = ox + dx*z, py = oy + dy*z, pz = oz + dz*z;
    const double inner = (fabs(px) <= SIDE && fabs(py) <= SIDE && fabs(pz) <= SIDE) ? 1.0 : 0.0;

    // neighbor (i+1) values
    const double next_s  = __shfl_down(s, 1);
    const double next_z  = __shfl_down(z, 1);
    const double inner_n = __shfl_down(inner, 1);

    // ---- interval quantities (valid for lane < 63) ----
    const double inside = ((inner > 0.5) || (inner_n > 0.5)) ? 1.0 : 0.0;
    const double mid    = 0.5 * (s + next_s);
    const double cv0    = (next_s - s) / (next_z - z + 1e-5);
    double prevc = __shfl_up(cv0, 1);
    if (lane == 0) prevc = 0.0;                        // prev_cos[0] = 0
    double cv = fmin(prevc, cv0);
    cv = fmin(fmax(cv, -1000.0), 0.0) * inside;        // clip * inside
    const double dist = next_z - z;

    // ---- alpha via merged sigmoids: ONE divide, TWO fast exps ----
    // pcdf = 1/(1+a), ncdf = 1/(1+b); a=exp(-arg_p), b=exp(-arg_n)
    // alpha = (pcdf-ncdf+1e-5)/(pcdf+1e-5)
    //       = ((b-a) + 1e-5*(1+a)(1+b)) / ((1+b) + 1e-5*(1+a)(1+b))
    // clamp +-350: sigmoid tails < 1e-152 (invisible under the 1e-5 terms),
    // and (1+a)(1+b) <= ~1e304 stays finite.
    const double arg_p = (mid - cv * dist * 0.5) * isv;
    const double arg_n = (mid + cv * dist * 0.5) * isv;
    const double a = exp_fast(fmin(fmax(-arg_p, -350.0), 350.0));
    const double b = exp_fast(fmin(fmax(-arg_n, -350.0), 350.0));
    const double P = (1.0 + a) * (1.0 + b);
    const double alpha = (__builtin_fma(1e-5, P, b - a)) /
                         (__builtin_fma(1e-5, P, 1.0 + b));

    // ---- exclusive cumprod of (1 - alpha + 1e-7): transmittance ----
    double g = (lane < 63) ? (1.0 - alpha + 1e-7) : 1.0;
    double p = g;
    #pragma unroll
    for (int off = 1; off < 64; off <<= 1) {
        double t = __shfl_up(p, off);
        if (lane >= off) p *= t;
    }
    double trans = __shfl_up(p, 1);
    if (lane == 0) trans = 1.0;

    // weights (+ sample_pdf's +1e-5); lane 63 holds 0 so scan total = sum
    const double w = (lane < 63) ? (alpha * trans + 1e-5) : 0.0;

    // ---- inclusive cumsum -> exclusive -> normalized CDF ----
    double sc = w;
    #pragma unroll
    for (int off = 1; off < 64; off <<= 1) {
        double t = __shfl_up(sc, off);
        if (lane >= off) sc += t;
    }
    const double total = __shfl(sc, 63);    // sum of all 63 weights
    const double excl  = sc - w;            // exclusive cumsum (lane0 -> 0)
    const double cdf   = excl / total;      // cdf[0]=0, cdf[63]=1

    // ---- searchsorted(cdf, u, side='right'): 7-step binary search ----
    // ind in [0,64]: 65 candidates -> ceil(log2(65)) = 7 halvings.
    // Guard lo<hi so early-converged lanes don't corrupt their answer;
    // __shfl stays unconditionally executed (wave-uniform control).
    const double u = u0 + du * (double)lane;   // exact multiples of 1/32
    int lo = 0, hi = 64;
    #pragma unroll
    for (int it = 0; it < 7; ++it) {
        const int m  = (lo + hi) >> 1;         // in [lo, hi)
        const double cm = __shfl(cdf, m);      // m<=63 always (hi<=64, lo<=hi)
        if (lo < hi) {
            if (cm <= u) lo = m + 1; else hi = m;
        }
    }                                          // after 7: lo == hi
    const int ind   = lo;                      // first idx with cdf > u
    const int below = max(ind - 1, 0);
    const int above = min(ind, 63);

    const double cb = __shfl(cdf, below);
    const double ca = __shfl(cdf, above);
    const double bb = __shfl(z, below);
    const double ba = __shfl(z, above);

    double denom = ca - cb;
    denom = (denom < 1e-5) ? 1.0 : denom;
    const double t   = (u - cb) / denom;
    const double res = bb + t * (ba - bb);

    if (lane < n_imp) out[(size_t)ray * n_imp + lane] = (float)res;
}

extern "C" void kernel_launch(void* const* d_in, const int* in_sizes, int n_in,
                              void* d_out, int out_size, void* d_ws, size_t ws_size,
                              hipStream_t stream) {
    const float* rays_o = (const float*)d_in[0];
    const float* rays_d = (const float*)d_in[1];
    const float* z_vals = (const float*)d_in[2];
    const float* sdf    = (const float*)d_in[3];
    const float* inv_s  = (const float*)d_in[4];
    float* out = (float*)d_out;

    const int B = in_sizes[0] / 3;          // 131072
    const int n = out_size / B;             // n_importance = 16
    const double u0 = 0.5 / (double)n;
    const double du = (n > 1) ? ((1.0 - 1.0 / (double)n) / (double)(n - 1)) : 0.0;

    const int grid = (B + 3) / 4;           // 4 waves (rays) per 256-thread block
    neus_sample_kernel<<<grid, 256, 0, stream>>>(rays_o, rays_d, z_vals, sdf, inv_s,
                                                 out, B, n, u0, du);
}

// Round 5
// 58.075 us; speedup vs baseline: 1.5166x; 1.4530x over previous
//
#include <hip/hip_runtime.h>
#include <math.h>

#define SIDE 0.6

// ---------- fast f64 exp, |x| <= 350, rel err ~1e-15 (validated round 3/4) ----------
__device__ __forceinline__ double exp_fast(double x) {
    const double INVLN2 = 1.44269504088896338700e+00;
    const double LN2HI  = 6.93147180369123816490e-01;
    const double LN2LO  = 1.90821492927058770002e-10;
    const double kd = __builtin_rint(x * INVLN2);
    const int    k  = (int)kd;
    double r = __builtin_fma(-kd, LN2HI, x);
    r        = __builtin_fma(-kd, LN2LO, r);
    double p =               2.08767569878681e-09;
    p = __builtin_fma(p, r,  2.50521083854417e-08);
    p = __builtin_fma(p, r,  2.75573192239859e-07);
    p = __builtin_fma(p, r,  2.75573192239859e-06);
    p = __builtin_fma(p, r,  2.48015873015873e-05);
    p = __builtin_fma(p, r,  1.98412698412698e-04);
    p = __builtin_fma(p, r,  1.38888888888889e-03);
    p = __builtin_fma(p, r,  8.33333333333333e-03);
    p = __builtin_fma(p, r,  4.16666666666667e-02);
    p = __builtin_fma(p, r,  1.66666666666667e-01);
    p = __builtin_fma(p, r,  5.00000000000000e-01);
    p = __builtin_fma(p, r,  1.0);
    p = __builtin_fma(p, r,  1.0);
    const long long bits = (long long)(1023 + k) << 52;
    return p * __longlong_as_double(bits);
}

// ---------- fast f32 exp, |x| <= 40, rel err ~2e-7 ----------
__device__ __forceinline__ float exp_fast_f(float x) {
    const float kd = rintf(x * 1.44269504f);
    const int   k  = (int)kd;
    float r = __builtin_fmaf(-kd, 0.693359375f, x);       // LN2HI (exact 10-bit)
    r       = __builtin_fmaf(kd, 2.12194440e-4f, r);      // -kd*LN2LO, LN2LO<0
    float p =                1.98412698e-4f;              // 1/7!
    p = __builtin_fmaf(p, r, 1.38888889e-3f);             // 1/6!
    p = __builtin_fmaf(p, r, 8.33333333e-3f);             // 1/5!
    p = __builtin_fmaf(p, r, 4.16666667e-2f);             // 1/4!
    p = __builtin_fmaf(p, r, 1.66666667e-1f);             // 1/3!
    p = __builtin_fmaf(p, r, 5.00000000e-1f);             // 1/2!
    p = __builtin_fmaf(p, r, 1.0f);
    p = __builtin_fmaf(p, r, 1.0f);
    return p * __int_as_float((127 + k) << 23);           // k in [-58,58]
}

// One 64-lane wave per ray (S = 64, lane == sample index).
// f32 fast path + flip-risk flags; flagged waves redo in the validated f64
// pipeline (matches the f64 numpy reference's discrete decisions).
__global__ __launch_bounds__(256) void neus_sample_kernel(
    const float* __restrict__ rays_o,
    const float* __restrict__ rays_d,
    const float* __restrict__ z_vals,
    const float* __restrict__ sdf,
    const float* __restrict__ inv_s,
    float* __restrict__ out,
    int B, int n_imp, double u0, double du)
{
    const int lane = threadIdx.x & 63;
    const int wave = threadIdx.x >> 6;
    const int ray  = blockIdx.x * 4 + wave;
    if (ray >= B) return;               // wave-uniform (B % 4 == 0 here)

    // ---- coalesced f32 loads (shared by both paths) ----
    const float zf = z_vals[(size_t)ray * 64 + lane];
    const float sf = sdf   [(size_t)ray * 64 + lane];
    float isvf = 0.0f;
    if (lane < 63) isvf = inv_s[(size_t)ray * 63 + lane];

    const float oxf = rays_o[(size_t)ray*3+0];
    const float oyf = rays_o[(size_t)ray*3+1];
    const float ozf = rays_o[(size_t)ray*3+2];
    const float dxf = rays_d[(size_t)ray*3+0];
    const float dyf = rays_d[(size_t)ray*3+1];
    const float dzf = rays_d[(size_t)ray*3+2];

    const float u0f = (float)u0, duf = (float)du;   // exact (multiples of 2^-6)

    // ================= f32 fast path + flip-risk flags =================
    int flag = 0;
    float res32 = 0.0f;
    {
        const float px = __builtin_fmaf(dxf, zf, oxf);
        const float py = __builtin_fmaf(dyf, zf, oyf);
        const float pz = __builtin_fmaf(dzf, zf, ozf);
        const float ax = fabsf(px), ay = fabsf(py), az = fabsf(pz);
        const float inner = (ax <= 0.6f && ay <= 0.6f && az <= 0.6f) ? 1.0f : 0.0f;
        // box-test flip band (f32 err ~2e-7; 50x margin)
        if (fabsf(ax - 0.6f) < 1e-5f || fabsf(ay - 0.6f) < 1e-5f ||
            fabsf(az - 0.6f) < 1e-5f) flag = 1;

        const float next_s  = __shfl_down(sf, 1);
        const float next_z  = __shfl_down(zf, 1);
        const float inner_n = __shfl_down(inner, 1);

        const float inside = ((inner > 0.5f) || (inner_n > 0.5f)) ? 1.0f : 0.0f;
        const float mid    = 0.5f * (sf + next_s);
        const float cv0    = (next_s - sf) / ((next_z - zf) + 1e-5f);
        float prevc = __shfl_up(cv0, 1);
        if (lane == 0) prevc = 0.0f;
        float cvv = fminf(prevc, cv0);
        cvv = fminf(fmaxf(cvv, -1000.0f), 0.0f) * inside;
        const float dist = next_z - zf;

        // merged sigmoids; clamp +-40 so a,b<=e^40 and P<=e^80 stay in f32 range;
        // beyond |arg|=12 the 1e-5 guards dominate, clamp error invisible.
        const float argp = (mid - cvv * dist * 0.5f) * isvf;
        const float argn = (mid + cvv * dist * 0.5f) * isvf;
        const float a = exp_fast_f(fminf(fmaxf(-argp, -40.0f), 40.0f));
        const float b = exp_fast_f(fminf(fmaxf(-argn, -40.0f), 40.0f));
        const float P    = (1.0f + a) * (1.0f + b);
        const float Nn   = __builtin_fmaf(1e-5f, P, b - a);
        const float Dd   = __builtin_fmaf(1e-5f, P, 1.0f + b);
        const float invD = 1.0f / Dd;
        const float alpha = Nn * invD;
        // stable 1-alpha+1e-7 = (1+a)/D + 1e-7 : no cancellation, g>0 always
        float g = (lane < 63) ? __builtin_fmaf(1.0f + a, invD, 1e-7f) : 1.0f;

        float p = g;
        #pragma unroll
        for (int off = 1; off < 64; off <<= 1) {
            float t = __shfl_up(p, off);
            if (lane >= off) p *= t;
        }
        float trans = __shfl_up(p, 1);
        if (lane == 0) trans = 1.0f;

        const float w = (lane < 63) ? __builtin_fmaf(alpha, trans, 1e-5f) : 0.0f;

        float sc = w;
        #pragma unroll
        for (int off = 1; off < 64; off <<= 1) {
            float t = __shfl_up(sc, off);
            if (lane >= off) sc += t;
        }
        const float total = __shfl(sc, 63);
        const float invT  = 1.0f / total;
        const float cdf   = (sc - w) * invT;

        // searchsorted flip band: this lane's cdf near its nearest u AND an
        // adjacent bin is thin (live-boundary flips are continuous -> safe)
        const float jn    = fminf(fmaxf(rintf((cdf - u0f) * (1.0f / duf)), 0.0f),
                                  (float)(n_imp - 1));
        const float unear = __builtin_fmaf(jn, duf, u0f);
        float wprev = __shfl_up(w, 1);
        if (lane == 0) wprev = w;     // cdf[0]=0 is never near a u anyway
        if (fabsf(cdf - unear) < 4e-5f && fminf(w, wprev) < 4e-3f * total)
            flag = 1;

        // 7-step guarded binary search (validated)
        const float u = __builtin_fmaf((float)lane, duf, u0f);
        int lo = 0, hi = 64;
        #pragma unroll
        for (int it = 0; it < 7; ++it) {
            const int m = (lo + hi) >> 1;
            const float cm = __shfl(cdf, m);
            if (lo < hi) {
                if (cm <= u) lo = m + 1; else hi = m;
            }
        }
        const int ind   = lo;
        const int below = max(ind - 1, 0);
        const int above = min(ind, 63);

        const float cb = __shfl(cdf, below);
        const float ca = __shfl(cdf, above);
        const float bb = __shfl(zf, below);
        const float ba = __shfl(zf, above);

        float denom = ca - cb;
        // thin selected bin: covers the denom<1e-5 branch band AND the
        // t=(u-cb)/denom error amplification (unflagged err <= 6e-5/4e-3*bin)
        if (lane < n_imp && denom < 4e-3f) flag = 1;
        denom = (denom < 1e-5f) ? 1.0f : denom;
        const float t = (u - cb) / denom;
        res32 = __builtin_fmaf(t, ba - bb, bb);
    }

    if (!__any(flag)) {
        if (lane < n_imp) out[(size_t)ray * n_imp + lane] = res32;
        return;                         // wave-uniform exit
    }

    // ================= f64 redo (round-4 validated path) =================
    const double z = (double)zf, s = (double)sf, isv = (double)isvf;
    const double ox = (double)oxf, oy = (double)oyf, oz = (double)ozf;
    const double dx = (double)dxf, dy = (double)dyf, dz = (double)dzf;

    const double px = ox + dx*z, py = oy + dy*z, pz = oz + dz*z;
    const double inner = (fabs(px) <= SIDE && fabs(py) <= SIDE && fabs(pz) <= SIDE) ? 1.0 : 0.0;

    const double next_s  = __shfl_down(s, 1);
    const double next_z  = __shfl_down(z, 1);
    const double inner_n = __shfl_down(inner, 1);

    const double inside = ((inner > 0.5) || (inner_n > 0.5)) ? 1.0 : 0.0;
    const double mid    = 0.5 * (s + next_s);
    const double cv0    = (next_s - s) / (next_z - z + 1e-5);
    double prevc = __shfl_up(cv0, 1);
    if (lane == 0) prevc = 0.0;
    double cv = fmin(prevc, cv0);
    cv = fmin(fmax(cv, -1000.0), 0.0) * inside;
    const double dist = next_z - z;

    const double arg_p = (mid - cv * dist * 0.5) * isv;
    const double arg_n = (mid + cv * dist * 0.5) * isv;
    const double a = exp_fast(fmin(fmax(-arg_p, -350.0), 350.0));
    const double b = exp_fast(fmin(fmax(-arg_n, -350.0), 350.0));
    const double P = (1.0 + a) * (1.0 + b);
    const double alpha = (__builtin_fma(1e-5, P, b - a)) /
                         (__builtin_fma(1e-5, P, 1.0 + b));

    double g = (lane < 63) ? (1.0 - alpha + 1e-7) : 1.0;
    double p = g;
    #pragma unroll
    for (int off = 1; off < 64; off <<= 1) {
        double t = __shfl_up(p, off);
        if (lane >= off) p *= t;
    }
    double trans = __shfl_up(p, 1);
    if (lane == 0) trans = 1.0;

    const double w = (lane < 63) ? (alpha * trans + 1e-5) : 0.0;

    double sc = w;
    #pragma unroll
    for (int off = 1; off < 64; off <<= 1) {
        double t = __shfl_up(sc, off);
        if (lane >= off) sc += t;
    }
    const double total = __shfl(sc, 63);
    const double excl  = sc - w;
    const double cdf   = excl / total;

    const double u = u0 + du * (double)lane;
    int lo = 0, hi = 64;
    #pragma unroll
    for (int it = 0; it < 7; ++it) {
        const int m  = (lo + hi) >> 1;
        const double cm = __shfl(cdf, m);
        if (lo < hi) {
            if (cm <= u) lo = m + 1; else hi = m;
        }
    }
    const int ind   = lo;
    const int below = max(ind - 1, 0);
    const int above = min(ind, 63);

    const double cb = __shfl(cdf, below);
    const double ca = __shfl(cdf, above);
    const double bb = __shfl(z, below);
    const double ba = __shfl(z, above);

    double denom = ca - cb;
    denom = (denom < 1e-5) ? 1.0 : denom;
    const double t   = (u - cb) / denom;
    const double res = bb + t * (ba - bb);

    if (lane < n_imp) out[(size_t)ray * n_imp + lane] = (float)res;
}

extern "C" void kernel_launch(void* const* d_in, const int* in_sizes, int n_in,
                              void* d_out, int out_size, void* d_ws, size_t ws_size,
                              hipStream_t stream) {
    const float* rays_o = (const float*)d_in[0];
    const float* rays_d = (const float*)d_in[1];
    const float* z_vals = (const float*)d_in[2];
    const float* sdf    = (const float*)d_in[3];
    const float* inv_s  = (const float*)d_in[4];
    float* out = (float*)d_out;

    const int B = in_sizes[0] / 3;          // 131072
    const int n = out_size / B;             // n_importance = 16
    const double u0 = 0.5 / (double)n;
    const double du = (n > 1) ? ((1.0 - 1.0 / (double)n) / (double)(n - 1)) : 0.0;

    const int grid = (B + 3) / 4;           // 4 waves (rays) per 256-thread block
    neus_sample_kernel<<<grid, 256, 0, stream>>>(rays_o, rays_d, z_vals, sdf, inv_s,
                                                 out, B, n, u0, du);
}